// Round 3
// baseline (110.350 us; speedup 1.0000x reference)
//
#include <hip/hip_runtime.h>
#include <hip/hip_bf16.h>

// B=8, C=64, O=64, H=W=128, stride=1, pad=1, 3x3 periphery conv + mask + 1x1 matmul.
constexpr int Bc = 8;
constexpr int Cc = 64;
constexpr int Oc = 64;
constexpr int Hc = 128;
constexpr int Wc = 128;
constexpr int HWc = Hc * Wc;
constexpr int CP = 72;   // LDS row stride (bf16 elems): 144 B -> 16B-aligned rows

typedef __attribute__((ext_vector_type(8))) short short8;   // 8 bf16 (4 VGPRs)
typedef __attribute__((ext_vector_type(4))) short short4v;  // 4 bf16 (8 B)
typedef __attribute__((ext_vector_type(4))) float floatx4;

// XOR-swizzle 16B blocks of the c-dimension by w to break the (stride 4w)
// bank-conflict pattern on agg writes while keeping b128 reads 16B-aligned.
__device__ __forceinline__ int swz(int w, int c) {
    return ((((c >> 3) ^ (w >> 2)) & 7) << 3) | (c & 7);
}

__device__ __forceinline__ short f2bf(float f) {
    __hip_bfloat16 h = __float2bfloat16(f);
    return *reinterpret_cast<short*>(&h);
}

// One block per (b,h) row, 512 threads = 8 waves.
// Thread = (wg = tid&31 -> 4 consecutive w, cg = tid>>5 -> 4 consecutive c).
// Phase 0: core (64x64) -> bf16 LDS (unswizzled).
// Phase 1: per channel load 3 float4 rows; w+-1 neighbors via shfl; compute
//          agg (8 taps, PERI weights) and div partials; zero-padding = zeroed
//          values. agg -> s_selT[w][swz(c)] (bf16, B^T layout for MFMA).
// Phase 2: mask[w] = ((div-thr)*scale)>0; where false overwrite sel with
//          center (rare path, exec-masked away).
// Phase 3: out[64o][128w] = core x sel via mfma_f32_16x16x32_bf16.
__global__ __launch_bounds__(512, 4) void spconv_kernel(
    const float* __restrict__ x, const float* __restrict__ core,
    const float* __restrict__ peri, const float* __restrict__ thr,
    const float* __restrict__ scl, float* __restrict__ out)
{
    __shared__ __hip_bfloat16 s_selT[Wc][CP];   // [w][c swizzled] 18432 B
    __shared__ __hip_bfloat16 s_core[Oc][CP];   // [o][c]           9216 B
    __shared__ float s_divp[16][Wc];            //                  8192 B
    __shared__ float s_msk[Wc];                 //                   512 B

    const int tid = threadIdx.x;
    const int wg  = tid & 31;
    const int cg  = tid >> 5;
    const int w0  = wg * 4;
    const int c0  = cg * 4;
    const int b   = blockIdx.x >> 7;
    const int h   = blockIdx.x & (Hc - 1);

    // ---- Phase 0: core -> bf16 LDS ----
    #pragma unroll
    for (int i = 0; i < 2; ++i) {
        const int idx = (i * 512 + tid) * 4;          // element index, x4
        const floatx4 cv = *(const floatx4*)&core[idx];
        short4v cv16 = { f2bf(cv.x), f2bf(cv.y), f2bf(cv.z), f2bf(cv.w) };
        *(short4v*)&s_core[idx >> 6][idx & 63] = cv16;
    }

    // ---- Phase 1 ----
    const float* xb = x + (size_t)b * Cc * HWc + (size_t)h * Wc;
    const bool hm = (h > 0), hp = (h < Hc - 1);

    float p[8];
    #pragma unroll
    for (int k = 0; k < 8; ++k) p[k] = peri[k];

    float div4[4] = {0.f, 0.f, 0.f, 0.f};
    float aggv[4][4];
    const floatx4 zero4 = {0.f, 0.f, 0.f, 0.f};

    #pragma unroll
    for (int ch = 0; ch < 4; ++ch) {
        const float* row = xb + (size_t)(c0 + ch) * HWc;
        const floatx4 tc = hm ? *(const floatx4*)(row - Wc + w0) : zero4;
        const floatx4 mc =      *(const floatx4*)(row      + w0);
        const floatx4 bc = hp ? *(const floatx4*)(row + Wc + w0) : zero4;

        // w-neighbors from adjacent lanes (width-32 groups == w-groups)
        float tl = __shfl_up(tc.w, 1, 32),  tr = __shfl_down(tc.x, 1, 32);
        float ml = __shfl_up(mc.w, 1, 32),  mr = __shfl_down(mc.x, 1, 32);
        float bl = __shfl_up(bc.w, 1, 32),  br = __shfl_down(bc.x, 1, 32);
        if (wg == 0)  { tl = 0.f; ml = 0.f; bl = 0.f; }   // w=0 left pad
        if (wg == 31) { tr = 0.f; mr = 0.f; br = 0.f; }   // w=127 right pad

        const float top[6] = {tl, tc.x, tc.y, tc.z, tc.w, tr};
        const float mid[6] = {ml, mc.x, mc.y, mc.z, mc.w, mr};
        const float bot[6] = {bl, bc.x, bc.y, bc.z, bc.w, br};

        #pragma unroll
        for (int j = 0; j < 4; ++j) {
            const float t4 = mid[j + 1];
            float a = p[0] * top[j];
            a = fmaf(p[1], top[j + 1], a);
            a = fmaf(p[2], top[j + 2], a);
            a = fmaf(p[3], mid[j],     a);
            a = fmaf(p[4], mid[j + 2], a);
            a = fmaf(p[5], bot[j],     a);
            a = fmaf(p[6], bot[j + 1], a);
            a = fmaf(p[7], bot[j + 2], a);
            aggv[ch][j] = a;

            float s = div4[j], d;
            d = top[j]     - t4; s = fmaf(d, d, s);
            d = top[j + 1] - t4; s = fmaf(d, d, s);
            d = top[j + 2] - t4; s = fmaf(d, d, s);
            d = mid[j]     - t4; s = fmaf(d, d, s);
            d = mid[j + 2] - t4; s = fmaf(d, d, s);
            d = bot[j]     - t4; s = fmaf(d, d, s);
            d = bot[j + 1] - t4; s = fmaf(d, d, s);
            d = bot[j + 2] - t4; s = fmaf(d, d, s);
            div4[j] = s;
        }
    }

    #pragma unroll
    for (int j = 0; j < 4; ++j) {
        short4v av = { f2bf(aggv[0][j]), f2bf(aggv[1][j]),
                       f2bf(aggv[2][j]), f2bf(aggv[3][j]) };
        *(short4v*)&s_selT[w0 + j][swz(w0 + j, c0)] = av;
    }
    floatx4 dv4 = {div4[0], div4[1], div4[2], div4[3]};
    *(floatx4*)&s_divp[cg][w0] = dv4;
    __syncthreads();

    // ---- Phase 2: mask + sel fixup ----
    if (tid < Wc) {
        float dv = 0.f;
        #pragma unroll
        for (int g = 0; g < 16; ++g) dv += s_divp[g][tid];
        s_msk[tid] = (((dv - thr[0]) * scl[0]) > 0.f) ? 1.f : 0.f;
    }
    __syncthreads();

    #pragma unroll
    for (int i = 0; i < 16; ++i) {                 // 8192 (c,w) pairs
        const int idx = i * 512 + tid;
        const int ww  = idx & (Wc - 1);
        const int c   = idx >> 7;
        if (s_msk[ww] == 0.f)                      // rare: div >> thr usually
            s_selT[ww][swz(ww, c)] = __float2bfloat16(xb[(size_t)c * HWc + ww]);
    }
    __syncthreads();

    // ---- Phase 3: MFMA GEMM D[o][w] = core[o][c] * sel[c][w], K=64 ----
    const int lane = tid & 63;
    const int wid  = tid >> 6;          // 0..7
    const int o0   = (wid & 3) * 16;
    const int wh   = wid >> 2;
    const int n    = lane & 15;
    const int quad = lane >> 4;

    const short8 a0 = *(const short8*)&s_core[o0 + n][quad * 8];
    const short8 a1 = *(const short8*)&s_core[o0 + n][quad * 8 + 32];

    float* outb = out + ((size_t)(b * Oc) * Hc + h) * Wc;

    #pragma unroll
    for (int t = 0; t < 4; ++t) {
        const int wq = (wh * 4 + t) * 16 + n;
        const short8 b0 = *(const short8*)&s_selT[wq][swz(wq, quad * 8)];
        const short8 b1 = *(const short8*)&s_selT[wq][swz(wq, quad * 8 + 32)];
        floatx4 acc = {0.f, 0.f, 0.f, 0.f};
        acc = __builtin_amdgcn_mfma_f32_16x16x32_bf16(a0, b0, acc, 0, 0, 0);
        acc = __builtin_amdgcn_mfma_f32_16x16x32_bf16(a1, b1, acc, 0, 0, 0);
        #pragma unroll
        for (int r = 0; r < 4; ++r) {
            const int o = o0 + quad * 4 + r;
            outb[(size_t)o * HWc + wq] = acc[r];
        }
    }
}

extern "C" void kernel_launch(void* const* d_in, const int* in_sizes, int n_in,
                              void* d_out, int out_size, void* d_ws, size_t ws_size,
                              hipStream_t stream) {
    const float* x    = (const float*)d_in[0];
    const float* core = (const float*)d_in[1];
    const float* peri = (const float*)d_in[2];
    const float* thr  = (const float*)d_in[3];
    const float* scl  = (const float*)d_in[4];
    float* out = (float*)d_out;

    spconv_kernel<<<dim3(Bc * Hc), dim3(512), 0, stream>>>(
        x, core, peri, thr, scl, out);
}